// Round 6
// baseline (201.518 us; speedup 1.0000x reference)
//
#include <hip/hip_runtime.h>
#include <math.h>
#include <stdint.h>

// B=4, C=256, H=W=64 -> HW=4096, C4=64
#define HWN 4096
#define CIN 256
#define CQ 64
#define LOG2E 1.44269504f
#define C2OFF 56.0f    // fixed softmax offset (exp2 domain); P kept in bf16
                       // (fp32 exponent range) -> tail-query underflow impossible

typedef __attribute__((ext_vector_type(8))) _Float16 f16x8;
typedef __attribute__((ext_vector_type(4))) _Float16 f16x4;
typedef __attribute__((ext_vector_type(8))) short    bf16x8;
typedef __attribute__((ext_vector_type(4))) short    bf16x4;
typedef __attribute__((ext_vector_type(4))) float    f32x4;

__device__ __forceinline__ short f2bf(float f) {
  union { float f; uint32_t u; } c; c.f = f;
  uint32_t r = (c.u + 0x7FFFu + ((c.u >> 16) & 1u)) >> 16;   // RNE
  return (short)(uint16_t)r;
}

// async global->LDS, 16B per lane; LDS dest = wave-uniform base + lane*16.
__device__ __forceinline__ void stage16(const void* g, void* l) {
  __builtin_amdgcn_global_load_lds(
      (const __attribute__((address_space(1))) uint32_t*)g,
      (__attribute__((address_space(3))) uint32_t*)l, 16, 0, 0);
}

// paired 16-lane-row swaps (gfx950 VALU, not LDS pipe):
// p32: a'=[a0,a1,b0,b1] b'=[a2,a3,b2,b3]   (rows = 16-lane groups)
// p16: a'=[a0,b0,a2,b2] b'=[a1,b1,a3,b3]
__device__ __forceinline__ void pswap32(uint32_t& a, uint32_t& b) {
  asm volatile("v_permlane32_swap_b32 %0, %1" : "+v"(a), "+v"(b));
}
__device__ __forceinline__ void pswap16(uint32_t& a, uint32_t& b) {
  asm volatile("v_permlane16_swap_b32 %0, %1" : "+v"(a), "+v"(b));
}

// ---------------------------------------------------------------- prep ----
__global__ __launch_bounds__(256) void prep_kernel(
    const float* __restrict__ Wqk, const float* __restrict__ Wkl,
    const float* __restrict__ Wkf, const float* __restrict__ Wv,
    const float* __restrict__ Wfire, const float* __restrict__ bfire,
    const float* __restrict__ gamma, const float* __restrict__ beta,
    const float* __restrict__ mean,  const float* __restrict__ var,
    _Float16* __restrict__ wqk_h, _Float16* __restrict__ wkl_h,
    _Float16* __restrict__ wkf_h, _Float16* __restrict__ wv_h,
    _Float16* __restrict__ wf_h, float* __restrict__ scale, float* __restrict__ shift) {
  int gid = blockIdx.x * 256 + threadIdx.x;
  if (gid < CQ * CIN) {
    wqk_h[gid] = (_Float16)(Wqk[gid] * LOG2E);
    wkl_h[gid] = (_Float16)Wkl[gid];
    wkf_h[gid] = (_Float16)Wkf[gid];
    wv_h[gid]  = (_Float16)Wv[gid];
  }
  if (gid < CIN * 128) wf_h[gid] = (_Float16)Wfire[gid];
  if (gid < CIN) {
    float inv = gamma[gid] / sqrtf(var[gid] + 1e-5f);
    scale[gid] = inv;
    shift[gid] = (bfire[gid] - mean[gid]) * inv + beta[gid];
  }
}

// ---------------------------------------------------------------- proj ----
// (unchanged) 3 passes, deep register prefetch, LDS transpose for kl/kf.
__global__ __launch_bounds__(256, 3) void proj_kernel(
    const float* __restrict__ cur, const float* __restrict__ last, const float* __restrict__ fut,
    const _Float16* __restrict__ wqk, const float* __restrict__ bqk,
    const _Float16* __restrict__ wkl, const float* __restrict__ bkl,
    const _Float16* __restrict__ wkf, const float* __restrict__ bkf,
    const _Float16* __restrict__ wv,  const float* __restrict__ bv,
    _Float16* __restrict__ q_out, _Float16* __restrict__ kl_out,
    _Float16* __restrict__ kf_out, short* __restrict__ v_out) {
  const int tid  = threadIdx.x;
  const int w    = tid >> 6;
  const int lane = tid & 63;
  const int quad = lane >> 4;
  const int l15  = lane & 15;
  const int pass = blockIdx.x >> 8;
  const int bb   = blockIdx.x & 255;
  const int b    = bb >> 6;
  const int hwt  = (bb & 63) << 6;
  const int hw   = hwt + w * 16 + l15;

  __shared__ __align__(16) _Float16 Tl[4][16][72];   // kl/kf transpose, 9 KB

  const float* X = (pass == 0) ? cur : ((pass == 1) ? last : fut);
  const float* xp = X + (size_t)b * CIN * HWN + hw;

  float xb[8][8];
#pragma unroll
  for (int c0 = 0; c0 < 8; ++c0)
#pragma unroll
    for (int j = 0; j < 8; ++j)
      xb[c0][j] = xp[(size_t)(c0 * 32 + quad * 8 + j) * HWN];

  if (pass == 0) {
    f32x4 aq[4] = {}; f32x4 av[4] = {};
#pragma unroll
    for (int k0 = 0; k0 < 8; ++k0) {
      f16x8 bh;
#pragma unroll
      for (int j = 0; j < 8; ++j) bh[j] = (_Float16)xb[k0][j];
#pragma unroll
      for (int mt = 0; mt < 4; ++mt) {
        f16x8 wa = *(const f16x8*)(wqk + (mt * 16 + l15) * CIN + k0 * 32 + quad * 8);
        aq[mt] = __builtin_amdgcn_mfma_f32_16x16x32_f16(wa, bh, aq[mt], 0, 0, 0);
        f16x8 wb = *(const f16x8*)(wv + (mt * 16 + l15) * CIN + k0 * 32 + quad * 8);
        av[mt] = __builtin_amdgcn_mfma_f32_16x16x32_f16(wb, bh, av[mt], 0, 0, 0);
      }
    }
#pragma unroll
    for (int mt = 0; mt < 4; ++mt)
#pragma unroll
      for (int r = 0; r < 4; ++r) {
        int oc = mt * 16 + quad * 4 + r;
        q_out[((size_t)b * CQ + oc) * HWN + hw] = (_Float16)(aq[mt][r] + bqk[oc] * LOG2E);
        v_out[((size_t)b * CQ + oc) * HWN + hw] = f2bf(av[mt][r] + bv[oc]);
      }
  } else {
    const _Float16* W = (pass == 1) ? wkl : wkf;
    const float* BI = (pass == 1) ? bkl : bkf;
    _Float16* OUT = (pass == 1) ? kl_out : kf_out;
    f32x4 a[4] = {};
#pragma unroll
    for (int k0 = 0; k0 < 8; ++k0) {
      f16x8 bh;
#pragma unroll
      for (int j = 0; j < 8; ++j) bh[j] = (_Float16)xb[k0][j];
#pragma unroll
      for (int mt = 0; mt < 4; ++mt) {
        f16x8 wa = *(const f16x8*)(W + (mt * 16 + l15) * CIN + k0 * 32 + quad * 8);
        a[mt] = __builtin_amdgcn_mfma_f32_16x16x32_f16(wa, bh, a[mt], 0, 0, 0);
      }
    }
#pragma unroll
    for (int mt = 0; mt < 4; ++mt) {
      f16x4 pw;
#pragma unroll
      for (int r = 0; r < 4; ++r)
        pw[r] = (_Float16)(a[mt][r] + BI[mt * 16 + quad * 4 + r]);
      *(f16x4*)&Tl[w][l15][mt * 16 + quad * 4] = pw;     // b64
    }
#pragma unroll
    for (int kk = 0; kk < 2; ++kk) {
      f16x8 row = *(const f16x8*)&Tl[w][l15][kk * 32 + quad * 8];   // b128
      *(f16x8*)(OUT + ((size_t)b * HWN + hw) * CQ + kk * 32 + quad * 8) = row;
    }
  }
}

// ---------------------------------------------------------------- attn ----
// R13: counted-vmcnt schedule (T4). __syncthreads' vmcnt(0) drain was the
// remaining stall (stall-bound: MfmaUtil 25 / VALUBusy 49 / pipes sum ~12us
// vs 57us measured). New loop: single body/iter; vmcnt(8)+s_barrier before
// compute (tile t done, t+1's 8 loads STAY IN FLIGHT), light s_barrier
// after compute, then stage t+2. Last iter peeled with vmcnt(0).
__global__ __launch_bounds__(256, 2) void attn_kernel(
    const _Float16* __restrict__ qbuf, const _Float16* __restrict__ klbuf,
    const _Float16* __restrict__ kfbuf, const short* __restrict__ vbuf,
    _Float16* __restrict__ fused) {
  const int tid  = threadIdx.x;
  const int w    = tid >> 6;
  const int lane = tid & 63;
  const int quad = lane >> 4;
  const int l15  = lane & 15;

  // XCD-aware decode: grid 512 = 8 XCDs x 64 blocks; one (b,pair) per XCD.
  const int xcd  = blockIdx.x & 7;
  const int L    = xcd * 64 + (blockIdx.x >> 3);
  const int qt   = (L & 63) << 6;          // 64 queries per block
  const int pair = (L >> 6) & 1;
  const int b    = L >> 7;

  const int kh = w >> 1;      // key half owned by this wave
  const int wq = w & 1;       // query half (32 q) within the block's 64

  const _Float16* K  = (pair ? kfbuf : klbuf) + (size_t)b * HWN * CQ;  // [key][c]
  const short*    Vg = vbuf + (size_t)b * CQ * HWN;                    // [c][key]

  __shared__ __align__(16) _Float16 Kt[2][2][64][64];  // [buf][kh][key][c] 32 KB
  __shared__ __align__(16) short    Vt[2][2][64][64];  // [buf][kh][c][key] 32 KB

  const int qbase = qt + wq * 32;
  f16x8 qfrag[2][2];
#pragma unroll
  for (int qg = 0; qg < 2; ++qg)
#pragma unroll
    for (int kk = 0; kk < 2; ++kk)
#pragma unroll
      for (int j = 0; j < 8; ++j)
        qfrag[qg][kk][j] = qbuf[(b * CQ + kk * 32 + quad * 8 + j) * HWN +
                                qbase + qg * 16 + l15];

  f32x4 Oacc[2][4] = {};       // [qg][ct]: row=q(quad*4+r), col=c4(ct*16+l15)
  float psum[2] = {0.f, 0.f};  // per-lane partial (q=l15 of qg, this quad's keys)

  const int swz  = (lane & 7) ^ ((lane >> 3) & 7);   // staging source chunk
  const int rswz = l15 & 7;                          // reader XOR key

  // staging source bases: this wave stages its wq-half (32 rows) of its kh tile
  const _Float16* ksrc =
      K + ((size_t)(kh * 2048) + wq * 32 + (lane >> 3)) * CQ + swz * 8;
  const short* vsrcS =
      Vg + (size_t)(wq * 32 + (lane >> 3)) * HWN + kh * 2048 + swz * 8;

  auto stageK = [&](int buf, int t) {       // t in [0,32): 4 loads
#pragma unroll
    for (int r = 0; r < 4; ++r)
      stage16(ksrc + ((size_t)t * 64 + r * 8) * CQ,
              &Kt[buf][kh][wq * 32 + r * 8][0]);
  };
  auto stageV = [&](int buf, int t) {       // 4 loads
#pragma unroll
    for (int r = 0; r < 4; ++r)
      stage16(vsrcS + (size_t)(r * 8) * HWN + t * 64,
              &Vt[buf][kh][wq * 32 + r * 8][0]);
  };

  auto body = [&](int buf) {
    // K fragments from LDS (XOR-swizzled), register-reused across both qg
    f16x8 kf[4][2];
#pragma unroll
    for (int nt = 0; nt < 4; ++nt)
#pragma unroll
      for (int kk = 0; kk < 2; ++kk)
        kf[nt][kk] = *(const f16x8*)&Kt[buf][kh][nt * 16 + l15][((kk * 4 + quad) ^ rswz) * 8];
    // V fragments from LDS, register-reused across both qg
    bf16x8 vf[4][2];
#pragma unroll
    for (int ct = 0; ct < 4; ++ct)
#pragma unroll
      for (int kk = 0; kk < 2; ++kk)
        vf[ct][kk] = *(const bf16x8*)&Vt[buf][kh][ct * 16 + l15][((kk * 4 + quad) ^ rswz) * 8];
#pragma unroll
    for (int qg = 0; qg < 2; ++qg) {
      f32x4 ST[4] = {};
      __builtin_amdgcn_s_setprio(1);
#pragma unroll
      for (int nt = 0; nt < 4; ++nt)
#pragma unroll
        for (int kk = 0; kk < 2; ++kk)
          ST[nt] = __builtin_amdgcn_mfma_f32_16x16x32_f16(kf[nt][kk], qfrag[qg][kk],
                                                          ST[nt], 0, 0, 0);
      __builtin_amdgcn_s_setprio(0);
      // exp2 -> truncated bf16 pairs (numerics identical to LDS path)
      uint32_t D[4][2];
#pragma unroll
      for (int nt = 0; nt < 4; ++nt)
#pragma unroll
        for (int e = 0; e < 2; ++e) {
          float p0 = __builtin_amdgcn_exp2f(ST[nt][2 * e]     - C2OFF);
          float p1 = __builtin_amdgcn_exp2f(ST[nt][2 * e + 1] - C2OFF);
          uint32_t u0 = __float_as_uint(p0) & 0xffff0000u;
          uint32_t u1 = __float_as_uint(p1) & 0xffff0000u;
          psum[qg] += __uint_as_float(u0) + __uint_as_float(u1);
          D[nt][e] = (u0 >> 16) | u1;          // low=key 2e, high=key 2e+1
        }
      // quad-transpose to PV A-layout + PV MFMAs
#pragma unroll
      for (int kk = 0; kk < 2; ++kk) {
        uint32_t pa0, pa1, pa2, pa3;
        {
          uint32_t u = D[2 * kk][0], v = D[2 * kk + 1][0];
          pswap32(u, v); pswap16(u, v);
          pa0 = u; pa2 = v;
        }
        {
          uint32_t u = D[2 * kk][1], v = D[2 * kk + 1][1];
          pswap32(u, v); pswap16(u, v);
          pa1 = u; pa3 = v;
        }
        union { uint32_t u[4]; bf16x8 v8; } P;
        P.u[0] = pa0; P.u[1] = pa1; P.u[2] = pa2; P.u[3] = pa3;
        __builtin_amdgcn_s_setprio(1);
#pragma unroll
        for (int ct = 0; ct < 4; ++ct)
          Oacc[qg][ct] = __builtin_amdgcn_mfma_f32_16x16x32_bf16(P.v8, vf[ct][kk],
                                                                 Oacc[qg][ct], 0, 0, 0);
        __builtin_amdgcn_s_setprio(0);
      }
    }
  };

  // prologue: two tiles in flight (16 loads)
  stageK(0, 0); stageV(0, 0);
  stageK(1, 1); stageV(1, 1);
#pragma unroll 1
  for (int t = 0; t < 31; ++t) {
    const int buf = t & 1;
    // (A) tile t ready: my 8 oldest loads done; tile t+1's 8 stay in flight
    asm volatile("s_waitcnt vmcnt(8)" ::: "memory");
    __builtin_amdgcn_s_barrier();
    __builtin_amdgcn_sched_barrier(0);
    body(buf);
    __builtin_amdgcn_sched_barrier(0);
    __builtin_amdgcn_s_barrier();        // (B) all waves done reading buf
    if (t + 2 < 32) { stageK(buf, t + 2); stageV(buf, t + 2); }
  }
  // peeled t=31 (only its own 8 loads outstanding)
  asm volatile("s_waitcnt vmcnt(0)" ::: "memory");
  __builtin_amdgcn_s_barrier();
  __builtin_amdgcn_sched_barrier(0);
  body(1);

  // reduce psum across quads within each wave
#pragma unroll
  for (int qg = 0; qg < 2; ++qg) {
    psum[qg] += __shfl_xor(psum[qg], 16);
    psum[qg] += __shfl_xor(psum[qg], 32);
  }

  __syncthreads();   // all Kt reads done before scratch reuse

  // cross-key-half combine through LDS scratch (Kt reuse; exact: fixed C2OFF)
  float* sc = (float*)&Kt[0][0][0][0];      // 16 KB O-partials
  float* sp = sc + 4096;                    // 1 KB psum-partials
  if (kh) {
#pragma unroll
    for (int qg = 0; qg < 2; ++qg) {
#pragma unroll
      for (int ct = 0; ct < 4; ++ct)
        *(f32x4*)&sc[((((wq * 2 + qg) * 4) + ct) << 8) + lane * 4] = Oacc[qg][ct];
      sp[(wq * 2 + qg) * 64 + lane] = psum[qg];
    }
  }
  __syncthreads();
  if (!kh) {
#pragma unroll
    for (int qg = 0; qg < 2; ++qg) {
      psum[qg] += sp[(wq * 2 + qg) * 64 + lane];
#pragma unroll
      for (int ct = 0; ct < 4; ++ct) {
        f32x4 o2 = *(const f32x4*)&sc[((((wq * 2 + qg) * 4) + ct) << 8) + lane * 4];
        Oacc[qg][ct] += o2;
      }
#pragma unroll
      for (int r = 0; r < 4; ++r) {
        float lt = __shfl(psum[qg], quad * 4 + r);   // row-sum lives at lane q
        float invl = __builtin_amdgcn_rcpf(lt);
        int qi = qbase + qg * 16 + quad * 4 + r;
#pragma unroll
        for (int ct = 0; ct < 4; ++ct)
          fused[((size_t)b * HWN + qi) * 128 + pair * 64 + ct * 16 + l15] =
              (_Float16)(Oacc[qg][ct][r] * invl);
      }
    }
  }
}

// ---------------------------------------------------------------- fire ----
// (unchanged) Wave = 16 hw x 64 oc; grid 1024.
__global__ __launch_bounds__(256) void fire_kernel(
    const _Float16* __restrict__ fused, const _Float16* __restrict__ wf,
    const float* __restrict__ scale, const float* __restrict__ shift,
    const float* __restrict__ cur, float* __restrict__ out) {
  const int tid  = threadIdx.x;
  const int w    = tid >> 6;
  const int lane = tid & 63;
  const int quad = lane >> 4;
  const int l15  = lane & 15;
  const int g    = blockIdx.x & 3;
  const int bb   = blockIdx.x >> 2;
  const int b    = bb >> 6;
  const int hwt  = (bb & 63) << 6;
  const int hwb  = hwt + w * 16;

  f16x8 bfr[4];
#pragma unroll
  for (int k0 = 0; k0 < 4; ++k0)
    bfr[k0] = *(const f16x8*)(fused + ((size_t)b * HWN + hwb + l15) * 128 + k0 * 32 + quad * 8);

  float curv[4][4];
#pragma unroll
  for (int mt = 0; mt < 4; ++mt)
#pragma unroll
    for (int r = 0; r < 4; ++r)
      curv[mt][r] = cur[((size_t)b * CIN + g * 64 + mt * 16 + quad * 4 + r) * HWN + hwb + l15];

  f32x4 acc[4] = {};
#pragma unroll
  for (int k0 = 0; k0 < 4; ++k0)
#pragma unroll
    for (int mt = 0; mt < 4; ++mt) {
      f16x8 af = *(const f16x8*)(wf + (g * 64 + mt * 16 + l15) * 128 + k0 * 32 + quad * 8);
      acc[mt] = __builtin_amdgcn_mfma_f32_16x16x32_f16(af, bfr[k0], acc[mt], 0, 0, 0);
    }

#pragma unroll
  for (int mt = 0; mt < 4; ++mt)
#pragma unroll
    for (int r = 0; r < 4; ++r) {
      int oc = g * 64 + mt * 16 + quad * 4 + r;
      size_t idx = ((size_t)b * CIN + oc) * HWN + hwb + l15;
      float y = curv[mt][r] + acc[mt][r] * scale[oc] + shift[oc];
      out[idx] = fmaxf(y, 0.f);
    }
}

// -------------------------------------------------------------- launch ----
extern "C" void kernel_launch(void* const* d_in, const int* in_sizes, int n_in,
                              void* d_out, int out_size, void* d_ws, size_t ws_size,
                              hipStream_t stream) {
  const float* last  = (const float*)d_in[0];
  const float* cur   = (const float*)d_in[1];
  const float* fut   = (const float*)d_in[2];
  const float* Wqk   = (const float*)d_in[3];
  const float* bqk   = (const float*)d_in[4];
  const float* Wkl   = (const float*)d_in[5];
  const float* bkl   = (const float*)d_in[6];
  const float* Wkf   = (const float*)d_in[7];
  const float* bkf   = (const float*)d_in[8];
  const float* Wv    = (const float*)d_in[9];
  const float* bv    = (const float*)d_in[10];
  const float* Wfire = (const float*)d_in[11];
  const float* bfire = (const float*)d_in[12];
  const float* gamma = (const float*)d_in[13];
  const float* beta  = (const float*)d_in[14];
  const float* mean  = (const float*)d_in[15];
  const float* var   = (const float*)d_in[16];

  char* ws = (char*)d_ws;
  _Float16* qb     = (_Float16*)(ws);                    // [4][64][4096]  2 MB
  _Float16* klb    = (_Float16*)(ws + (2u << 20));       // [4][4096][64]  2 MB
  _Float16* kfb    = (_Float16*)(ws + (4u << 20));       // [4][4096][64]  2 MB
  short*    vb     = (short*)   (ws + (6u << 20));       // [4][64][4096]  2 MB bf16
  _Float16* fusedb = (_Float16*)(ws + (8u << 20));       // [4][4096][128] 4 MB
  char* wsm = ws + (12u << 20);
  _Float16* wqk_h = (_Float16*)(wsm);
  _Float16* wkl_h = (_Float16*)(wsm + (32u << 10));
  _Float16* wkf_h = (_Float16*)(wsm + (64u << 10));
  _Float16* wv_h  = (_Float16*)(wsm + (96u << 10));
  _Float16* wf_h  = (_Float16*)(wsm + (128u << 10));
  float*    scale = (float*)   (wsm + (192u << 10));
  float*    shift = (float*)   (wsm + (193u << 10));
  float*    out   = (float*)d_out;

  prep_kernel<<<128, 256, 0, stream>>>(Wqk, Wkl, Wkf, Wv, Wfire, bfire,
                                       gamma, beta, mean, var,
                                       wqk_h, wkl_h, wkf_h, wv_h, wf_h, scale, shift);
  proj_kernel<<<768, 256, 0, stream>>>(cur, last, fut, wqk_h, bqk, wkl_h, bkl,
                                       wkf_h, bkf, wv_h, bv, qb, klb, kfb, vb);
  attn_kernel<<<512, 256, 0, stream>>>(qb, klb, kfb, vb, fusedb);
  fire_kernel<<<1024, 256, 0, stream>>>(fusedb, wf_h, scale, shift, cur, out);
}

// Round 7
// 194.905 us; speedup vs baseline: 1.0339x; 1.0339x over previous
//
#include <hip/hip_runtime.h>
#include <math.h>
#include <stdint.h>

// B=4, C=256, H=W=64 -> HW=4096, C4=64
#define HWN 4096
#define CIN 256
#define CQ 64
#define LOG2E 1.44269504f
#define C2OFF 56.0f    // fixed softmax offset (exp2 domain); P kept in bf16
                       // (fp32 exponent range) -> tail-query underflow impossible

typedef __attribute__((ext_vector_type(8))) _Float16 f16x8;
typedef __attribute__((ext_vector_type(4))) _Float16 f16x4;
typedef __attribute__((ext_vector_type(8))) short    bf16x8;
typedef __attribute__((ext_vector_type(4))) short    bf16x4;
typedef __attribute__((ext_vector_type(4))) float    f32x4;

__device__ __forceinline__ short f2bf(float f) {
  union { float f; uint32_t u; } c; c.f = f;
  uint32_t r = (c.u + 0x7FFFu + ((c.u >> 16) & 1u)) >> 16;   // RNE
  return (short)(uint16_t)r;
}

// async global->LDS, 16B per lane; LDS dest = wave-uniform base + lane*16.
__device__ __forceinline__ void stage16(const void* g, void* l) {
  __builtin_amdgcn_global_load_lds(
      (const __attribute__((address_space(1))) uint32_t*)g,
      (__attribute__((address_space(3))) uint32_t*)l, 16, 0, 0);
}

// paired 16-lane-row swaps (gfx950 VALU, not LDS pipe):
// p32: a'=[a0,a1,b0,b1] b'=[a2,a3,b2,b3]   (rows = 16-lane groups)
// p16: a'=[a0,b0,a2,b2] b'=[a1,b1,a3,b3]
__device__ __forceinline__ void pswap32(uint32_t& a, uint32_t& b) {
  asm volatile("v_permlane32_swap_b32 %0, %1" : "+v"(a), "+v"(b));
}
__device__ __forceinline__ void pswap16(uint32_t& a, uint32_t& b) {
  asm volatile("v_permlane16_swap_b32 %0, %1" : "+v"(a), "+v"(b));
}

// ---------------------------------------------------------------- prep ----
__global__ __launch_bounds__(256) void prep_kernel(
    const float* __restrict__ Wqk, const float* __restrict__ Wkl,
    const float* __restrict__ Wkf, const float* __restrict__ Wv,
    const float* __restrict__ Wfire, const float* __restrict__ bfire,
    const float* __restrict__ gamma, const float* __restrict__ beta,
    const float* __restrict__ mean,  const float* __restrict__ var,
    _Float16* __restrict__ wqk_h, _Float16* __restrict__ wkl_h,
    _Float16* __restrict__ wkf_h, _Float16* __restrict__ wv_h,
    _Float16* __restrict__ wf_h, float* __restrict__ scale, float* __restrict__ shift) {
  int gid = blockIdx.x * 256 + threadIdx.x;
  if (gid < CQ * CIN) {
    wqk_h[gid] = (_Float16)(Wqk[gid] * LOG2E);
    wkl_h[gid] = (_Float16)Wkl[gid];
    wkf_h[gid] = (_Float16)Wkf[gid];
    wv_h[gid]  = (_Float16)Wv[gid];
  }
  if (gid < CIN * 128) wf_h[gid] = (_Float16)Wfire[gid];
  if (gid < CIN) {
    float inv = gamma[gid] / sqrtf(var[gid] + 1e-5f);
    scale[gid] = inv;
    shift[gid] = (bfire[gid] - mean[gid]) * inv + beta[gid];
  }
}

// ---------------------------------------------------------------- proj ----
// R14: HBM-coalesced restructure. Old: 64 scalar f32 loads/thread, each
// wave-instr = 4 x 64B segments 128KB apart (scattered short streams,
// ~15-25% HBM class) + 64-VGPR prefetch chain. New: async global_load_lds
// staging of X in CONTIGUOUS 256B c-row streams (4 rows = 1KB per instr),
// double-buffered 32-channel chunks, MFMA B-frags via LDS b32 reads.
// LDS groups = [4c][64hw] f32 + 16B pad (1040B) so quad-strided reads are
// <=2-way bank conflicts (free). Accumulation order identical to R13.
__global__ __launch_bounds__(256, 3) void proj_kernel(
    const float* __restrict__ cur, const float* __restrict__ last, const float* __restrict__ fut,
    const _Float16* __restrict__ wqk, const float* __restrict__ bqk,
    const _Float16* __restrict__ wkl, const float* __restrict__ bkl,
    const _Float16* __restrict__ wkf, const float* __restrict__ bkf,
    const _Float16* __restrict__ wv,  const float* __restrict__ bv,
    _Float16* __restrict__ q_out, _Float16* __restrict__ kl_out,
    _Float16* __restrict__ kf_out, short* __restrict__ v_out) {
  const int tid  = threadIdx.x;
  const int w    = tid >> 6;
  const int lane = tid & 63;
  const int quad = lane >> 4;
  const int l15  = lane & 15;
  const int pass = blockIdx.x >> 8;
  const int bb   = blockIdx.x & 255;
  const int b    = bb >> 6;
  const int hwt  = (bb & 63) << 6;
  const int hw   = hwt + w * 16 + l15;

  // Xs: [buf][8 groups][260 f32]; group = [4c][64hw] + 4-dword pad (1040B)
  __shared__ __align__(16) float    Xs[2][8][260];   // 16.25 KB
  __shared__ __align__(16) _Float16 Tl[4][16][72];   // kl/kf transpose, 9 KB

  const float* X = (pass == 0) ? cur : ((pass == 1) ? last : fut);
  const float* xb0 = X + (size_t)b * CIN * HWN + hwt;

  // stage chunk cc (32 c-rows x 64 hw): wave w stages local rows w*8..w*8+7
  // via 2 instrs; per instr: 4 c-rows, lane -> row=lane>>4, hwchunk=(lane&15)
  auto stageX = [&](int buf, int cc) {
#pragma unroll
    for (int i = 0; i < 2; ++i)
      stage16(xb0 + (size_t)(cc * 32 + w * 8 + i * 4 + (lane >> 3) / 2) * HWN +
                  ((lane & 15) << 2),
              &Xs[buf][w * 2 + i][0]);
  };

  const _Float16* W1 = (pass == 0) ? wqk : ((pass == 1) ? wkl : wkf);
  f32x4 a1[4] = {};   // qk or kl/kf
  f32x4 a2[4] = {};   // v (pass 0 only)

  stageX(0, 0);
  __syncthreads();
#pragma unroll 1
  for (int cc = 0; cc < 8; ++cc) {
    const int buf = cc & 1;
    if (cc + 1 < 8) stageX(buf ^ 1, cc + 1);
    // B-frag: bh[j] = X[cc*32 + quad*8 + j][w*16+l15]
    f16x8 bh;
#pragma unroll
    for (int j = 0; j < 8; ++j) {
      const int g = quad * 2 + (j >> 2);
      bh[j] = (_Float16)Xs[buf][g][(j & 3) * 64 + w * 16 + l15];
    }
#pragma unroll
    for (int mt = 0; mt < 4; ++mt) {
      f16x8 wa = *(const f16x8*)(W1 + (mt * 16 + l15) * CIN + cc * 32 + quad * 8);
      a1[mt] = __builtin_amdgcn_mfma_f32_16x16x32_f16(wa, bh, a1[mt], 0, 0, 0);
    }
    if (pass == 0) {
#pragma unroll
      for (int mt = 0; mt < 4; ++mt) {
        f16x8 wb = *(const f16x8*)(wv + (mt * 16 + l15) * CIN + cc * 32 + quad * 8);
        a2[mt] = __builtin_amdgcn_mfma_f32_16x16x32_f16(wb, bh, a2[mt], 0, 0, 0);
      }
    }
    __syncthreads();   // drains staging of cc+1; guards buf reuse
  }

  if (pass == 0) {
#pragma unroll
    for (int mt = 0; mt < 4; ++mt)
#pragma unroll
      for (int r = 0; r < 4; ++r) {
        int oc = mt * 16 + quad * 4 + r;
        q_out[((size_t)b * CQ + oc) * HWN + hw] = (_Float16)(a1[mt][r] + bqk[oc] * LOG2E);
        v_out[((size_t)b * CQ + oc) * HWN + hw] = f2bf(a2[mt][r] + bv[oc]);
      }
  } else {
    const float* BI = (pass == 1) ? bkl : bkf;
    _Float16* OUT = (pass == 1) ? kl_out : kf_out;
#pragma unroll
    for (int mt = 0; mt < 4; ++mt) {
      f16x4 pw;
#pragma unroll
      for (int r = 0; r < 4; ++r)
        pw[r] = (_Float16)(a1[mt][r] + BI[mt * 16 + quad * 4 + r]);
      *(f16x4*)&Tl[w][l15][mt * 16 + quad * 4] = pw;     // b64
    }
#pragma unroll
    for (int kk = 0; kk < 2; ++kk) {
      f16x8 row = *(const f16x8*)&Tl[w][l15][kk * 32 + quad * 8];   // b128
      *(f16x8*)(OUT + ((size_t)b * HWN + hw) * CQ + kk * 32 + quad * 8) = row;
    }
  }
}

// ---------------------------------------------------------------- attn ----
// R12 schedule restored (57us proven; R13's counted-vmcnt + extra barriers
// regressed to 65 because R12's stage-before-body already covers the
// syncthreads vmcnt drain). P transpose stays in registers via permlane.
__global__ __launch_bounds__(256, 2) void attn_kernel(
    const _Float16* __restrict__ qbuf, const _Float16* __restrict__ klbuf,
    const _Float16* __restrict__ kfbuf, const short* __restrict__ vbuf,
    _Float16* __restrict__ fused) {
  const int tid  = threadIdx.x;
  const int w    = tid >> 6;
  const int lane = tid & 63;
  const int quad = lane >> 4;
  const int l15  = lane & 15;

  // XCD-aware decode: grid 512 = 8 XCDs x 64 blocks; one (b,pair) per XCD.
  const int xcd  = blockIdx.x & 7;
  const int L    = xcd * 64 + (blockIdx.x >> 3);
  const int qt   = (L & 63) << 6;          // 64 queries per block
  const int pair = (L >> 6) & 1;
  const int b    = L >> 7;

  const int kh = w >> 1;      // key half owned by this wave
  const int wq = w & 1;       // query half (32 q) within the block's 64

  const _Float16* K  = (pair ? kfbuf : klbuf) + (size_t)b * HWN * CQ;  // [key][c]
  const short*    Vg = vbuf + (size_t)b * CQ * HWN;                    // [c][key]

  __shared__ __align__(16) _Float16 Kt[2][2][64][64];  // [buf][kh][key][c] 32 KB
  __shared__ __align__(16) short    Vt[2][2][64][64];  // [buf][kh][c][key] 32 KB

  const int qbase = qt + wq * 32;
  f16x8 qfrag[2][2];
#pragma unroll
  for (int qg = 0; qg < 2; ++qg)
#pragma unroll
    for (int kk = 0; kk < 2; ++kk)
#pragma unroll
      for (int j = 0; j < 8; ++j)
        qfrag[qg][kk][j] = qbuf[(b * CQ + kk * 32 + quad * 8 + j) * HWN +
                                qbase + qg * 16 + l15];

  f32x4 Oacc[2][4] = {};       // [qg][ct]: row=q(quad*4+r), col=c4(ct*16+l15)
  float psum[2] = {0.f, 0.f};  // per-lane partial (q=l15 of qg, this quad's keys)

  const int swz  = (lane & 7) ^ ((lane >> 3) & 7);   // staging source chunk
  const int rswz = l15 & 7;                          // reader XOR key

  // staging source bases: this wave stages its wq-half (32 rows) of its kh tile
  const _Float16* ksrc =
      K + ((size_t)(kh * 2048) + wq * 32 + (lane >> 3)) * CQ + swz * 8;
  const short* vsrcS =
      Vg + (size_t)(wq * 32 + (lane >> 3)) * HWN + kh * 2048 + swz * 8;

  auto stageK = [&](int buf, int t) {       // t in [0,32): 4 loads
#pragma unroll
    for (int r = 0; r < 4; ++r)
      stage16(ksrc + ((size_t)t * 64 + r * 8) * CQ,
              &Kt[buf][kh][wq * 32 + r * 8][0]);
  };
  auto stageV = [&](int buf, int t) {       // 4 loads
#pragma unroll
    for (int r = 0; r < 4; ++r)
      stage16(vsrcS + (size_t)(r * 8) * HWN + t * 64,
              &Vt[buf][kh][wq * 32 + r * 8][0]);
  };

  auto body = [&](int buf) {
    // K fragments from LDS (XOR-swizzled), register-reused across both qg
    f16x8 kf[4][2];
#pragma unroll
    for (int nt = 0; nt < 4; ++nt)
#pragma unroll
      for (int kk = 0; kk < 2; ++kk)
        kf[nt][kk] = *(const f16x8*)&Kt[buf][kh][nt * 16 + l15][((kk * 4 + quad) ^ rswz) * 8];
    // V fragments from LDS, register-reused across both qg
    bf16x8 vf[4][2];
#pragma unroll
    for (int ct = 0; ct < 4; ++ct)
#pragma unroll
      for (int kk = 0; kk < 2; ++kk)
        vf[ct][kk] = *(const bf16x8*)&Vt[buf][kh][ct * 16 + l15][((kk * 4 + quad) ^ rswz) * 8];
#pragma unroll
    for (int qg = 0; qg < 2; ++qg) {
      f32x4 ST[4] = {};
      __builtin_amdgcn_s_setprio(1);
#pragma unroll
      for (int nt = 0; nt < 4; ++nt)
#pragma unroll
        for (int kk = 0; kk < 2; ++kk)
          ST[nt] = __builtin_amdgcn_mfma_f32_16x16x32_f16(kf[nt][kk], qfrag[qg][kk],
                                                          ST[nt], 0, 0, 0);
      __builtin_amdgcn_s_setprio(0);
      // exp2 -> truncated bf16 pairs (numerics identical to LDS path)
      uint32_t D[4][2];
#pragma unroll
      for (int nt = 0; nt < 4; ++nt)
#pragma unroll
        for (int e = 0; e < 2; ++e) {
          float p0 = __builtin_amdgcn_exp2f(ST[nt][2 * e]     - C2OFF);
          float p1 = __builtin_amdgcn_exp2f(ST[nt][2 * e + 1] - C2OFF);
          uint32_t u0 = __float_as_uint(p0) & 0xffff0000u;
          uint32_t u1 = __float_as_uint(p1) & 0xffff0000u;
          psum[qg] += __uint_as_float(u0) + __uint_as_float(u1);
          D[nt][e] = (u0 >> 16) | u1;          // low=key 2e, high=key 2e+1
        }
      // quad-transpose to PV A-layout + PV MFMAs
#pragma unroll
      for (int kk = 0; kk < 2; ++kk) {
        uint32_t pa0, pa1, pa2, pa3;
        {
          uint32_t u = D[2 * kk][0], v = D[2 * kk + 1][0];
          pswap32(u, v); pswap16(u, v);
          pa0 = u; pa2 = v;
        }
        {
          uint32_t u = D[2 * kk][1], v = D[2 * kk + 1][1];
          pswap32(u, v); pswap16(u, v);
          pa1 = u; pa3 = v;
        }
        union { uint32_t u[4]; bf16x8 v8; } P;
        P.u[0] = pa0; P.u[1] = pa1; P.u[2] = pa2; P.u[3] = pa3;
        __builtin_amdgcn_s_setprio(1);
#pragma unroll
        for (int ct = 0; ct < 4; ++ct)
          Oacc[qg][ct] = __builtin_amdgcn_mfma_f32_16x16x32_bf16(P.v8, vf[ct][kk],
                                                                 Oacc[qg][ct], 0, 0, 0);
        __builtin_amdgcn_s_setprio(0);
      }
    }
  };

  stageK(0, 0); stageV(0, 0);
  __syncthreads();
#pragma unroll 1
  for (int tt = 0; tt < 32; tt += 2) {
    stageK(1, tt + 1); stageV(1, tt + 1);     // tt+1 <= 31 always
    body(0);
    __syncthreads();                           // drains staging of tt+1
    if (tt + 2 < 32) { stageK(0, tt + 2); stageV(0, tt + 2); }
    body(1);
    __syncthreads();
  }

  // reduce psum across quads within each wave
#pragma unroll
  for (int qg = 0; qg < 2; ++qg) {
    psum[qg] += __shfl_xor(psum[qg], 16);
    psum[qg] += __shfl_xor(psum[qg], 32);
  }

  // cross-key-half combine through LDS scratch (Kt reuse; exact: fixed C2OFF)
  float* sc = (float*)&Kt[0][0][0][0];      // 16 KB O-partials
  float* sp = sc + 4096;                    // 1 KB psum-partials
  if (kh) {
#pragma unroll
    for (int qg = 0; qg < 2; ++qg) {
#pragma unroll
      for (int ct = 0; ct < 4; ++ct)
        *(f32x4*)&sc[((((wq * 2 + qg) * 4) + ct) << 8) + lane * 4] = Oacc[qg][ct];
      sp[(wq * 2 + qg) * 64 + lane] = psum[qg];
    }
  }
  __syncthreads();
  if (!kh) {
#pragma unroll
    for (int qg = 0; qg < 2; ++qg) {
      psum[qg] += sp[(wq * 2 + qg) * 64 + lane];
#pragma unroll
      for (int ct = 0; ct < 4; ++ct) {
        f32x4 o2 = *(const f32x4*)&sc[((((wq * 2 + qg) * 4) + ct) << 8) + lane * 4];
        Oacc[qg][ct] += o2;
      }
#pragma unroll
      for (int r = 0; r < 4; ++r) {
        float lt = __shfl(psum[qg], quad * 4 + r);   // row-sum lives at lane q
        float invl = __builtin_amdgcn_rcpf(lt);
        int qi = qbase + qg * 16 + quad * 4 + r;
#pragma unroll
        for (int ct = 0; ct < 4; ++ct)
          fused[((size_t)b * HWN + qi) * 128 + pair * 64 + ct * 16 + l15] =
              (_Float16)(Oacc[qg][ct][r] * invl);
      }
    }
  }
}

// ---------------------------------------------------------------- fire ----
// (unchanged) Wave = 16 hw x 64 oc; grid 1024.
__global__ __launch_bounds__(256) void fire_kernel(
    const _Float16* __restrict__ fused, const _Float16* __restrict__ wf,
    const float* __restrict__ scale, const float* __restrict__ shift,
    const float* __restrict__ cur, float* __restrict__ out) {
  const int tid  = threadIdx.x;
  const int w    = tid >> 6;
  const int lane = tid & 63;
  const int quad = lane >> 4;
  const int l15  = lane & 15;
  const int g    = blockIdx.x & 3;
  const int bb   = blockIdx.x >> 2;
  const int b    = bb >> 6;
  const int hwt  = (bb & 63) << 6;
  const int hwb  = hwt + w * 16;

  f16x8 bfr[4];
#pragma unroll
  for (int k0 = 0; k0 < 4; ++k0)
    bfr[k0] = *(const f16x8*)(fused + ((size_t)b * HWN + hwb + l15) * 128 + k0 * 32 + quad * 8);

  float curv[4][4];
#pragma unroll
  for (int mt = 0; mt < 4; ++mt)
#pragma unroll
    for (int r = 0; r < 4; ++r)
      curv[mt][r] = cur[((size_t)b * CIN + g * 64 + mt * 16 + quad * 4 + r) * HWN + hwb + l15];

  f32x4 acc[4] = {};
#pragma unroll
  for (int k0 = 0; k0 < 4; ++k0)
#pragma unroll
    for (int mt = 0; mt < 4; ++mt) {
      f16x8 af = *(const f16x8*)(wf + (g * 64 + mt * 16 + l15) * 128 + k0 * 32 + quad * 8);
      acc[mt] = __builtin_amdgcn_mfma_f32_16x16x32_f16(af, bfr[k0], acc[mt], 0, 0, 0);
    }

#pragma unroll
  for (int mt = 0; mt < 4; ++mt)
#pragma unroll
    for (int r = 0; r < 4; ++r) {
      int oc = g * 64 + mt * 16 + quad * 4 + r;
      size_t idx = ((size_t)b * CIN + oc) * HWN + hwb + l15;
      float y = curv[mt][r] + acc[mt][r] * scale[oc] + shift[oc];
      out[idx] = fmaxf(y, 0.f);
    }
}

// -------------------------------------------------------------- launch ----
extern "C" void kernel_launch(void* const* d_in, const int* in_sizes, int n_in,
                              void* d_out, int out_size, void* d_ws, size_t ws_size,
                              hipStream_t stream) {
  const float* last  = (const float*)d_in[0];
  const float* cur   = (const float*)d_in[1];
  const float* fut   = (const float*)d_in[2];
  const float* Wqk   = (const float*)d_in[3];
  const float* bqk   = (const float*)d_in[4];
  const float* Wkl   = (const float*)d_in[5];
  const float* bkl   = (const float*)d_in[6];
  const float* Wkf   = (const float*)d_in[7];
  const float* bkf   = (const float*)d_in[8];
  const float* Wv    = (const float*)d_in[9];
  const float* bv    = (const float*)d_in[10];
  const float* Wfire = (const float*)d_in[11];
  const float* bfire = (const float*)d_in[12];
  const float* gamma = (const float*)d_in[13];
  const float* beta  = (const float*)d_in[14];
  const float* mean  = (const float*)d_in[15];
  const float* var   = (const float*)d_in[16];

  char* ws = (char*)d_ws;
  _Float16* qb     = (_Float16*)(ws);                    // [4][64][4096]  2 MB
  _Float16* klb    = (_Float16*)(ws + (2u << 20));       // [4][4096][64]  2 MB
  _Float16* kfb    = (_Float16*)(ws + (4u << 20));       // [4][4096][64]  2 MB
  short*    vb     = (short*)   (ws + (6u << 20));       // [4][64][4096]  2 MB bf16
  _Float16* fusedb = (_Float16*)(ws + (8u << 20));       // [4][4096][128] 4 MB
  char* wsm = ws + (12u << 20);
  _Float16* wqk_h = (_Float16*)(wsm);
  _Float16* wkl_h = (_Float16*)(wsm + (32u << 10));
  _Float16* wkf_h = (_Float16*)(wsm + (64u << 10));
  _Float16* wv_h  = (_Float16*)(wsm + (96u << 10));
  _Float16* wf_h  = (_Float16*)(wsm + (128u << 10));
  float*    scale = (float*)   (wsm + (192u << 10));
  float*    shift = (float*)   (wsm + (193u << 10));
  float*    out   = (float*)d_out;

  prep_kernel<<<128, 256, 0, stream>>>(Wqk, Wkl, Wkf, Wv, Wfire, bfire,
                                       gamma, beta, mean, var,
                                       wqk_h, wkl_h, wkf_h, wv_h, wf_h, scale, shift);
  proj_kernel<<<768, 256, 0, stream>>>(cur, last, fut, wqk_h, bqk, wkl_h, bkl,
                                       wkf_h, bkf, wv_h, bv, qb, klb, kfb, vb);
  attn_kernel<<<512, 256, 0, stream>>>(qb, klb, kfb, vb, fusedb);
  fire_kernel<<<1024, 256, 0, stream>>>(fusedb, wf_h, scale, shift, cur, out);
}

// Round 8
// 193.581 us; speedup vs baseline: 1.0410x; 1.0068x over previous
//
#include <hip/hip_runtime.h>
#include <math.h>
#include <stdint.h>

// B=4, C=256, H=W=64 -> HW=4096, C4=64
#define HWN 4096
#define CIN 256
#define CQ 64
#define LOG2E 1.44269504f
#define C2OFF 56.0f    // fixed softmax offset (exp2 domain); P kept in bf16
                       // (fp32 exponent range) -> tail-query underflow impossible

typedef __attribute__((ext_vector_type(8))) _Float16 f16x8;
typedef __attribute__((ext_vector_type(4))) _Float16 f16x4;
typedef __attribute__((ext_vector_type(8))) short    bf16x8;
typedef __attribute__((ext_vector_type(4))) short    bf16x4;
typedef __attribute__((ext_vector_type(4))) float    f32x4;

__device__ __forceinline__ short f2bf(float f) {
  union { float f; uint32_t u; } c; c.f = f;
  uint32_t r = (c.u + 0x7FFFu + ((c.u >> 16) & 1u)) >> 16;   // RNE
  return (short)(uint16_t)r;
}

// async global->LDS, 16B per lane; LDS dest = wave-uniform base + lane*16.
__device__ __forceinline__ void stage16(const void* g, void* l) {
  __builtin_amdgcn_global_load_lds(
      (const __attribute__((address_space(1))) uint32_t*)g,
      (__attribute__((address_space(3))) uint32_t*)l, 16, 0, 0);
}

// paired 16-lane-row swaps (gfx950 VALU, not LDS pipe):
// p32: a'=[a0,a1,b0,b1] b'=[a2,a3,b2,b3]   (rows = 16-lane groups)
// p16: a'=[a0,b0,a2,b2] b'=[a1,b1,a3,b3]
__device__ __forceinline__ void pswap32(uint32_t& a, uint32_t& b) {
  asm volatile("v_permlane32_swap_b32 %0, %1" : "+v"(a), "+v"(b));
}
__device__ __forceinline__ void pswap16(uint32_t& a, uint32_t& b) {
  asm volatile("v_permlane16_swap_b32 %0, %1" : "+v"(a), "+v"(b));
}

// ---------------------------------------------------------------- prep ----
__global__ __launch_bounds__(256) void prep_kernel(
    const float* __restrict__ Wqk, const float* __restrict__ Wkl,
    const float* __restrict__ Wkf, const float* __restrict__ Wv,
    const float* __restrict__ Wfire, const float* __restrict__ bfire,
    const float* __restrict__ gamma, const float* __restrict__ beta,
    const float* __restrict__ mean,  const float* __restrict__ var,
    _Float16* __restrict__ wqk_h, _Float16* __restrict__ wkl_h,
    _Float16* __restrict__ wkf_h, _Float16* __restrict__ wv_h,
    _Float16* __restrict__ wf_h, float* __restrict__ scale, float* __restrict__ shift) {
  int gid = blockIdx.x * 256 + threadIdx.x;
  if (gid < CQ * CIN) {
    wqk_h[gid] = (_Float16)(Wqk[gid] * LOG2E);
    wkl_h[gid] = (_Float16)Wkl[gid];
    wkf_h[gid] = (_Float16)Wkf[gid];
    wv_h[gid]  = (_Float16)Wv[gid];
  }
  if (gid < CIN * 128) wf_h[gid] = (_Float16)Wfire[gid];
  if (gid < CIN) {
    float inv = gamma[gid] / sqrtf(var[gid] + 1e-5f);
    scale[gid] = inv;
    shift[gid] = (bfire[gid] - mean[gid]) * inv + beta[gid];
  }
}

// ---------------------------------------------------------------- proj ----
// (R14 version kept: async contiguous staging; neutral vs old but cleaner.)
__global__ __launch_bounds__(256, 3) void proj_kernel(
    const float* __restrict__ cur, const float* __restrict__ last, const float* __restrict__ fut,
    const _Float16* __restrict__ wqk, const float* __restrict__ bqk,
    const _Float16* __restrict__ wkl, const float* __restrict__ bkl,
    const _Float16* __restrict__ wkf, const float* __restrict__ bkf,
    const _Float16* __restrict__ wv,  const float* __restrict__ bv,
    _Float16* __restrict__ q_out, _Float16* __restrict__ kl_out,
    _Float16* __restrict__ kf_out, short* __restrict__ v_out) {
  const int tid  = threadIdx.x;
  const int w    = tid >> 6;
  const int lane = tid & 63;
  const int quad = lane >> 4;
  const int l15  = lane & 15;
  const int pass = blockIdx.x >> 8;
  const int bb   = blockIdx.x & 255;
  const int b    = bb >> 6;
  const int hwt  = (bb & 63) << 6;
  const int hw   = hwt + w * 16 + l15;

  // Xs: [buf][8 groups][260 f32]; group = [4c][64hw] + 4-dword pad (1040B)
  __shared__ __align__(16) float    Xs[2][8][260];   // 16.25 KB
  __shared__ __align__(16) _Float16 Tl[4][16][72];   // kl/kf transpose, 9 KB

  const float* X = (pass == 0) ? cur : ((pass == 1) ? last : fut);
  const float* xb0 = X + (size_t)b * CIN * HWN + hwt;

  auto stageX = [&](int buf, int cc) {
#pragma unroll
    for (int i = 0; i < 2; ++i)
      stage16(xb0 + (size_t)(cc * 32 + w * 8 + i * 4 + (lane >> 3) / 2) * HWN +
                  ((lane & 15) << 2),
              &Xs[buf][w * 2 + i][0]);
  };

  const _Float16* W1 = (pass == 0) ? wqk : ((pass == 1) ? wkl : wkf);
  f32x4 a1[4] = {};   // qk or kl/kf
  f32x4 a2[4] = {};   // v (pass 0 only)

  stageX(0, 0);
  __syncthreads();
#pragma unroll 1
  for (int cc = 0; cc < 8; ++cc) {
    const int buf = cc & 1;
    if (cc + 1 < 8) stageX(buf ^ 1, cc + 1);
    // B-frag: bh[j] = X[cc*32 + quad*8 + j][w*16+l15]
    f16x8 bh;
#pragma unroll
    for (int j = 0; j < 8; ++j) {
      const int g = quad * 2 + (j >> 2);
      bh[j] = (_Float16)Xs[buf][g][(j & 3) * 64 + w * 16 + l15];
    }
#pragma unroll
    for (int mt = 0; mt < 4; ++mt) {
      f16x8 wa = *(const f16x8*)(W1 + (mt * 16 + l15) * CIN + cc * 32 + quad * 8);
      a1[mt] = __builtin_amdgcn_mfma_f32_16x16x32_f16(wa, bh, a1[mt], 0, 0, 0);
    }
    if (pass == 0) {
#pragma unroll
      for (int mt = 0; mt < 4; ++mt) {
        f16x8 wb = *(const f16x8*)(wv + (mt * 16 + l15) * CIN + cc * 32 + quad * 8);
        a2[mt] = __builtin_amdgcn_mfma_f32_16x16x32_f16(wb, bh, a2[mt], 0, 0, 0);
      }
    }
    __syncthreads();   // drains staging of cc+1; guards buf reuse
  }

  if (pass == 0) {
#pragma unroll
    for (int mt = 0; mt < 4; ++mt)
#pragma unroll
      for (int r = 0; r < 4; ++r) {
        int oc = mt * 16 + quad * 4 + r;
        q_out[((size_t)b * CQ + oc) * HWN + hw] = (_Float16)(a1[mt][r] + bqk[oc] * LOG2E);
        v_out[((size_t)b * CQ + oc) * HWN + hw] = f2bf(a2[mt][r] + bv[oc]);
      }
  } else {
    const float* BI = (pass == 1) ? bkl : bkf;
    _Float16* OUT = (pass == 1) ? kl_out : kf_out;
#pragma unroll
    for (int mt = 0; mt < 4; ++mt) {
      f16x4 pw;
#pragma unroll
      for (int r = 0; r < 4; ++r)
        pw[r] = (_Float16)(a1[mt][r] + BI[mt * 16 + quad * 4 + r]);
      *(f16x4*)&Tl[w][l15][mt * 16 + quad * 4] = pw;     // b64
    }
#pragma unroll
    for (int kk = 0; kk < 2; ++kk) {
      f16x8 row = *(const f16x8*)&Tl[w][l15][kk * 32 + quad * 8];   // b128
      *(f16x8*)(OUT + ((size_t)b * HWN + hw) * CQ + kk * 32 + quad * 8) = row;
    }
  }
}

// ---------------------------------------------------------------- attn ----
// R15: kill the VALU serialization in the body.
//  * psum -> ones-MFMA row-sum: Osum[qg] = mfma(P, ones_bf16, Osum).
//    +2 MFMA/qg (no LDS: B-frag is a register constant) replaces 32 serial
//    VALU adds/body AND the epilogue shfl_xor reduce (row-sum for
//    q=quad*4+r lands in Osum[qg][r], all cols equal).
//  * truncate-pack -> v_cvt_pk_bf16_f32 (1 VALU/pair vs ~3-4; RNE).
//  Schedule unchanged from R12 (56.5us baseline).
__global__ __launch_bounds__(256, 2) void attn_kernel(
    const _Float16* __restrict__ qbuf, const _Float16* __restrict__ klbuf,
    const _Float16* __restrict__ kfbuf, const short* __restrict__ vbuf,
    _Float16* __restrict__ fused) {
  const int tid  = threadIdx.x;
  const int w    = tid >> 6;
  const int lane = tid & 63;
  const int quad = lane >> 4;
  const int l15  = lane & 15;

  // XCD-aware decode: grid 512 = 8 XCDs x 64 blocks; one (b,pair) per XCD.
  const int xcd  = blockIdx.x & 7;
  const int L    = xcd * 64 + (blockIdx.x >> 3);
  const int qt   = (L & 63) << 6;          // 64 queries per block
  const int pair = (L >> 6) & 1;
  const int b    = L >> 7;

  const int kh = w >> 1;      // key half owned by this wave
  const int wq = w & 1;       // query half (32 q) within the block's 64

  const _Float16* K  = (pair ? kfbuf : klbuf) + (size_t)b * HWN * CQ;  // [key][c]
  const short*    Vg = vbuf + (size_t)b * CQ * HWN;                    // [c][key]

  __shared__ __align__(16) _Float16 Kt[2][2][64][64];  // [buf][kh][key][c] 32 KB
  __shared__ __align__(16) short    Vt[2][2][64][64];  // [buf][kh][c][key] 32 KB

  const int qbase = qt + wq * 32;
  f16x8 qfrag[2][2];
#pragma unroll
  for (int qg = 0; qg < 2; ++qg)
#pragma unroll
    for (int kk = 0; kk < 2; ++kk)
#pragma unroll
      for (int j = 0; j < 8; ++j)
        qfrag[qg][kk][j] = qbuf[(b * CQ + kk * 32 + quad * 8 + j) * HWN +
                                qbase + qg * 16 + l15];

  f32x4 Oacc[2][4] = {};       // [qg][ct]: row=q(quad*4+r), col=c4(ct*16+l15)
  f32x4 Osum[2]    = {};       // P row-sums: row=q(quad*4+r), cols all equal

  bf16x8 vones;                // constant all-ones bf16 B-fragment
#pragma unroll
  for (int j = 0; j < 8; ++j) vones[j] = (short)0x3F80;

  const int swz  = (lane & 7) ^ ((lane >> 3) & 7);   // staging source chunk
  const int rswz = l15 & 7;                          // reader XOR key

  // staging source bases: this wave stages its wq-half (32 rows) of its kh tile
  const _Float16* ksrc =
      K + ((size_t)(kh * 2048) + wq * 32 + (lane >> 3)) * CQ + swz * 8;
  const short* vsrcS =
      Vg + (size_t)(wq * 32 + (lane >> 3)) * HWN + kh * 2048 + swz * 8;

  auto stageK = [&](int buf, int t) {       // t in [0,32): 4 loads
#pragma unroll
    for (int r = 0; r < 4; ++r)
      stage16(ksrc + ((size_t)t * 64 + r * 8) * CQ,
              &Kt[buf][kh][wq * 32 + r * 8][0]);
  };
  auto stageV = [&](int buf, int t) {       // 4 loads
#pragma unroll
    for (int r = 0; r < 4; ++r)
      stage16(vsrcS + (size_t)(r * 8) * HWN + t * 64,
              &Vt[buf][kh][wq * 32 + r * 8][0]);
  };

  auto body = [&](int buf) {
    // K fragments from LDS (XOR-swizzled), register-reused across both qg
    f16x8 kf[4][2];
#pragma unroll
    for (int nt = 0; nt < 4; ++nt)
#pragma unroll
      for (int kk = 0; kk < 2; ++kk)
        kf[nt][kk] = *(const f16x8*)&Kt[buf][kh][nt * 16 + l15][((kk * 4 + quad) ^ rswz) * 8];
    // V fragments from LDS, register-reused across both qg
    bf16x8 vf[4][2];
#pragma unroll
    for (int ct = 0; ct < 4; ++ct)
#pragma unroll
      for (int kk = 0; kk < 2; ++kk)
        vf[ct][kk] = *(const bf16x8*)&Vt[buf][kh][ct * 16 + l15][((kk * 4 + quad) ^ rswz) * 8];
#pragma unroll
    for (int qg = 0; qg < 2; ++qg) {
      f32x4 ST[4] = {};
      __builtin_amdgcn_s_setprio(1);
#pragma unroll
      for (int nt = 0; nt < 4; ++nt)
#pragma unroll
        for (int kk = 0; kk < 2; ++kk)
          ST[nt] = __builtin_amdgcn_mfma_f32_16x16x32_f16(kf[nt][kk], qfrag[qg][kk],
                                                          ST[nt], 0, 0, 0);
      __builtin_amdgcn_s_setprio(0);
      // exp2 -> packed bf16 pairs (RNE via cvt_pk; no serial psum chain)
      uint32_t D[4][2];
#pragma unroll
      for (int nt = 0; nt < 4; ++nt)
#pragma unroll
        for (int e = 0; e < 2; ++e) {
          float p0 = __builtin_amdgcn_exp2f(ST[nt][2 * e]     - C2OFF);
          float p1 = __builtin_amdgcn_exp2f(ST[nt][2 * e + 1] - C2OFF);
          asm("v_cvt_pk_bf16_f32 %0, %1, %2"
              : "=v"(D[nt][e]) : "v"(p0), "v"(p1));   // low=key 2e, high=2e+1
        }
      // quad-transpose to PV A-layout + PV MFMAs (+ ones row-sum MFMA)
#pragma unroll
      for (int kk = 0; kk < 2; ++kk) {
        uint32_t pa0, pa1, pa2, pa3;
        {
          uint32_t u = D[2 * kk][0], v = D[2 * kk + 1][0];
          pswap32(u, v); pswap16(u, v);
          pa0 = u; pa2 = v;
        }
        {
          uint32_t u = D[2 * kk][1], v = D[2 * kk + 1][1];
          pswap32(u, v); pswap16(u, v);
          pa1 = u; pa3 = v;
        }
        union { uint32_t u[4]; bf16x8 v8; } P;
        P.u[0] = pa0; P.u[1] = pa1; P.u[2] = pa2; P.u[3] = pa3;
        __builtin_amdgcn_s_setprio(1);
#pragma unroll
        for (int ct = 0; ct < 4; ++ct)
          Oacc[qg][ct] = __builtin_amdgcn_mfma_f32_16x16x32_bf16(P.v8, vf[ct][kk],
                                                                 Oacc[qg][ct], 0, 0, 0);
        Osum[qg] = __builtin_amdgcn_mfma_f32_16x16x32_bf16(P.v8, vones,
                                                           Osum[qg], 0, 0, 0);
        __builtin_amdgcn_s_setprio(0);
      }
    }
  };

  stageK(0, 0); stageV(0, 0);
  __syncthreads();
#pragma unroll 1
  for (int tt = 0; tt < 32; tt += 2) {
    stageK(1, tt + 1); stageV(1, tt + 1);     // tt+1 <= 31 always
    body(0);
    __syncthreads();                           // drains staging of tt+1
    if (tt + 2 < 32) { stageK(0, tt + 2); stageV(0, tt + 2); }
    body(1);
    __syncthreads();
  }

  // cross-key-half combine through LDS scratch (Kt reuse; exact: fixed C2OFF)
  float* sc = (float*)&Kt[0][0][0][0];      // 16 KB Oacc partials
  f32x4* sv = (f32x4*)(sc + 4096);          // 4 KB Osum partials
  if (kh) {
#pragma unroll
    for (int qg = 0; qg < 2; ++qg) {
#pragma unroll
      for (int ct = 0; ct < 4; ++ct)
        *(f32x4*)&sc[((((wq * 2 + qg) * 4) + ct) << 8) + lane * 4] = Oacc[qg][ct];
      sv[(wq * 2 + qg) * 64 + lane] = Osum[qg];
    }
  }
  __syncthreads();
  if (!kh) {
#pragma unroll
    for (int qg = 0; qg < 2; ++qg) {
      Osum[qg] += sv[(wq * 2 + qg) * 64 + lane];
#pragma unroll
      for (int ct = 0; ct < 4; ++ct) {
        f32x4 o2 = *(const f32x4*)&sc[((((wq * 2 + qg) * 4) + ct) << 8) + lane * 4];
        Oacc[qg][ct] += o2;
      }
#pragma unroll
      for (int r = 0; r < 4; ++r) {
        float invl = __builtin_amdgcn_rcpf(Osum[qg][r]);   // row-sum, no shfl
        int qi = qbase + qg * 16 + quad * 4 + r;
#pragma unroll
        for (int ct = 0; ct < 4; ++ct)
          fused[((size_t)b * HWN + qi) * 128 + pair * 64 + ct * 16 + l15] =
              (_Float16)(Oacc[qg][ct][r] * invl);
      }
    }
  }
}

// ---------------------------------------------------------------- fire ----
// R15: XCD-chunked decode so the 4 g-blocks sharing one fused window land
// on the SAME XCD L2 (default round-robin fetched fused 4x from HBM).
__global__ __launch_bounds__(256) void fire_kernel(
    const _Float16* __restrict__ fused, const _Float16* __restrict__ wf,
    const float* __restrict__ scale, const float* __restrict__ shift,
    const float* __restrict__ cur, float* __restrict__ out) {
  const int tid  = threadIdx.x;
  const int w    = tid >> 6;
  const int lane = tid & 63;
  const int quad = lane >> 4;
  const int l15  = lane & 15;
  const int xcd  = blockIdx.x & 7;
  const int Lf   = xcd * 128 + (blockIdx.x >> 3);   // 1024 = 8 XCDs x 128
  const int g    = Lf & 3;
  const int bb   = Lf >> 2;
  const int b    = bb >> 6;
  const int hwt  = (bb & 63) << 6;
  const int hwb  = hwt + w * 16;

  f16x8 bfr[4];
#pragma unroll
  for (int k0 = 0; k0 < 4; ++k0)
    bfr[k0] = *(const f16x8*)(fused + ((size_t)b * HWN + hwb + l15) * 128 + k0 * 32 + quad * 8);

  float curv[4][4];
#pragma unroll
  for (int mt = 0; mt < 4; ++mt)
#pragma unroll
    for (int r = 0; r < 4; ++r)
      curv[mt][r] = cur[((size_t)b * CIN + g * 64 + mt * 16 + quad * 4 + r) * HWN + hwb + l15];

  f32x4 acc[4] = {};
#pragma unroll
  for (int k0 = 0; k0 < 4; ++k0)
#pragma unroll
    for (int mt = 0; mt < 4; ++mt) {
      f16x8 af = *(const f16x8*)(wf + (g * 64 + mt * 16 + l15) * 128 + k0 * 32 + quad * 8);
      acc[mt] = __builtin_amdgcn_mfma_f32_16x16x32_f16(af, bfr[k0], acc[mt], 0, 0, 0);
    }

#pragma unroll
  for (int mt = 0; mt < 4; ++mt)
#pragma unroll
    for (int r = 0; r < 4; ++r) {
      int oc = g * 64 + mt * 16 + quad * 4 + r;
      size_t idx = ((size_t)b * CIN + oc) * HWN + hwb + l15;
      float y = curv[mt][r] + acc[mt][r] * scale[oc] + shift[oc];
      out[idx] = fmaxf(y, 0.f);
    }
}

// -------------------------------------------------------------- launch ----
extern "C" void kernel_launch(void* const* d_in, const int* in_sizes, int n_in,
                              void* d_out, int out_size, void* d_ws, size_t ws_size,
                              hipStream_t stream) {
  const float* last  = (const float*)d_in[0];
  const float* cur   = (const float*)d_in[1];
  const float* fut   = (const float*)d_in[2];
  const float* Wqk   = (const float*)d_in[3];
  const float* bqk   = (const float*)d_in[4];
  const float* Wkl   = (const float*)d_in[5];
  const float* bkl   = (const float*)d_in[6];
  const float* Wkf   = (const float*)d_in[7];
  const float* bkf   = (const float*)d_in[8];
  const float* Wv    = (const float*)d_in[9];
  const float* bv    = (const float*)d_in[10];
  const float* Wfire = (const float*)d_in[11];
  const float* bfire = (const float*)d_in[12];
  const float* gamma = (const float*)d_in[13];
  const float* beta  = (const float*)d_in[14];
  const float* mean  = (const float*)d_in[15];
  const float* var   = (const float*)d_in[16];

  char* ws = (char*)d_ws;
  _Float16* qb     = (_Float16*)(ws);                    // [4][64][4096]  2 MB
  _Float16* klb    = (_Float16*)(ws + (2u << 20));       // [4][4096][64]  2 MB
  _Float16* kfb    = (_Float16*)(ws + (4u << 20));       // [4][4096][64]  2 MB
  short*    vb     = (short*)   (ws + (6u << 20));       // [4][64][4096]  2 MB bf16
  _Float16* fusedb = (_Float16*)(ws + (8u << 20));       // [4][4096][128] 4 MB
  char* wsm = ws + (12u << 20);
  _Float16* wqk_h = (_Float16*)(wsm);
  _Float16* wkl_h = (_Float16*)(wsm + (32u << 10));
  _Float16* wkf_h = (_Float16*)(wsm + (64u << 10));
  _Float16* wv_h  = (_Float16*)(wsm + (96u << 10));
  _Float16* wf_h  = (_Float16*)(wsm + (128u << 10));
  float*    scale = (float*)   (wsm + (192u << 10));
  float*    shift = (float*)   (wsm + (193u << 10));
  float*    out   = (float*)d_out;

  prep_kernel<<<128, 256, 0, stream>>>(Wqk, Wkl, Wkf, Wv, Wfire, bfire,
                                       gamma, beta, mean, var,
                                       wqk_h, wkl_h, wkf_h, wv_h, wf_h, scale, shift);
  proj_kernel<<<768, 256, 0, stream>>>(cur, last, fut, wqk_h, bqk, wkl_h, bkl,
                                       wkf_h, bkf, wv_h, bv, qb, klb, kfb, vb);
  attn_kernel<<<512, 256, 0, stream>>>(qb, klb, kfb, vb, fusedb);
  fire_kernel<<<1024, 256, 0, stream>>>(fusedb, wf_h, scale, shift, cur, out);
}